// Round 5
// baseline (286.876 us; speedup 1.0000x reference)
//
#include <hip/hip_runtime.h>
#include <hip/hip_bf16.h>

typedef short s8v __attribute__((ext_vector_type(8)));
typedef float f4v __attribute__((ext_vector_type(4)));

#define MFMA16(A,B,C) __builtin_amdgcn_mfma_f32_16x16x32_bf16((A),(B),(C),0,0,0)

#define E_TOT 245760
#define N_TOT 98304

__device__ __forceinline__ unsigned short f2bf(float f) {
    unsigned u = __builtin_bit_cast(unsigned, f);
    u += 0x7fffu + ((u >> 16) & 1u);
    return (unsigned short)(u >> 16);
}
__device__ __forceinline__ float bflo(unsigned u) {
    return __builtin_bit_cast(float, u << 16);
}
__device__ __forceinline__ float bfhi(unsigned u) {
    return __builtin_bit_cast(float, u & 0xffff0000u);
}

// ---------------------------------------------------------------- pack ----
// w1p : [12nt][64][8]            6144   bf16   (K 30->32 pad)      pos-space
// w2p : [22c][2t][6s][64][8]     135168 bf16 (per-c stride 6144)   src-space
// l1p : [6nt][12s][64][8]        36864  bf16                       src-space
// l2p : [3nt][3s][64][8]         4608   bf16                       src-space
// l3p : [9nt][2s][64][8]         9216   bf16  (K->64, N->144 pad)  pos-space
__global__ void pack_kernel(const float* __restrict__ w1, const float* __restrict__ w2,
                            const float* __restrict__ l1w, const float* __restrict__ l2w,
                            const float* __restrict__ l3w,
                            unsigned short* __restrict__ w1p, unsigned short* __restrict__ w2p,
                            unsigned short* __restrict__ l1p, unsigned short* __restrict__ l2p,
                            unsigned short* __restrict__ l3p)
{
    int idx = blockIdx.x * 256 + threadIdx.x;
    if (idx >= 192000) return;
    if (idx < 6144) {                       // w1p, position-space (padded)
        int i = idx & 7, l = (idx >> 3) & 63, nt = idx >> 9;
        int k = (l >> 4) * 8 + i, col = nt * 16 + (l & 15);
        w1p[idx] = f2bf(k < 30 ? w1[k * 192 + col] : 0.f);
    } else if (idx < 141312) {              // w2p, source-space (coalesced reads)
        int e = idx - 6144;
        int k = e / 704, j = e - k * 704;
        int c = j >> 5, t = (j >> 4) & 1, colv = j & 15;
        int s = k >> 5, hi = (k >> 3) & 3, i = k & 7;
        w2p[((c * 2 + t) * 6 + s) * 512 + (hi * 16 + colv) * 8 + i] = f2bf(w2[e]);
    } else if (idx < 178176) {              // l1p, source-space
        int e = idx - 141312;
        int k = e / 96, j = e - k * 96;
        int s = k >> 5, hi = (k >> 3) & 3, i = k & 7;
        int nt = j >> 4, colv = j & 15;
        l1p[(nt * 12 + s) * 512 + (hi * 16 + colv) * 8 + i] = f2bf(l1w[e]);
    } else if (idx < 182784) {              // l2p, source-space
        int e = idx - 178176;
        int k = e / 48, j = e - k * 48;
        int s = k >> 5, hi = (k >> 3) & 3, i = k & 7;
        int nt = j >> 4, colv = j & 15;
        l2p[(nt * 3 + s) * 512 + (hi * 16 + colv) * 8 + i] = f2bf(l2w[e]);
    } else {                                // l3p, position-space (padded)
        int e = idx - 182784;
        int i = e & 7, l = (e >> 3) & 63, rest = e >> 9;
        int s = rest & 1, nt = rest >> 1;
        int k = s * 32 + (l >> 4) * 8 + i, j = nt * 16 + (l & 15);
        l3p[e] = f2bf((k < 48 && j < 132) ? l3w[k * 132 + j] : 0.f);
    }
}

// ------------------------------------------------------------- init ----
// agg = x @ root1 + bias1   (f32; edge atomics accumulate on top)
__launch_bounds__(256)
__global__ void init_kernel(const float* __restrict__ x, const float* __restrict__ root1,
                            const float* __restrict__ bias1, float* __restrict__ agg)
{
    const int tid = threadIdx.x, wave = tid >> 6, lane = tid & 63;
    const int hi = lane >> 4, col = lane & 15;
    const int n0 = blockIdx.x * 256 + wave * 64;

    s8v bfr[2];
#pragma unroll
    for (int nt = 0; nt < 2; ++nt)
#pragma unroll
        for (int i = 0; i < 8; ++i) {
            int k = hi * 8 + i;
            bfr[nt][i] = (short)f2bf(k < 22 ? root1[k * 32 + nt * 16 + col] : 0.f);
        }
    float bb0 = bias1[col], bb1 = bias1[16 + col];

#pragma unroll
    for (int mt = 0; mt < 4; ++mt) {
        int node = n0 + mt * 16 + col;
        s8v af;
        if (hi < 2) {
            const float2* p = (const float2*)&x[node * 22 + hi * 8];
            float2 t0 = p[0], t1 = p[1], t2 = p[2], t3 = p[3];
            af[0] = (short)f2bf(t0.x); af[1] = (short)f2bf(t0.y);
            af[2] = (short)f2bf(t1.x); af[3] = (short)f2bf(t1.y);
            af[4] = (short)f2bf(t2.x); af[5] = (short)f2bf(t2.y);
            af[6] = (short)f2bf(t3.x); af[7] = (short)f2bf(t3.y);
        } else if (hi == 2) {
            const float2* p = (const float2*)&x[node * 22 + 16];
            float2 t0 = p[0], t1 = p[1], t2 = p[2];
            af[0] = (short)f2bf(t0.x); af[1] = (short)f2bf(t0.y);
            af[2] = (short)f2bf(t1.x); af[3] = (short)f2bf(t1.y);
            af[4] = (short)f2bf(t2.x); af[5] = (short)f2bf(t2.y);
            af[6] = 0; af[7] = 0;
        } else {
            af = (s8v)0;
        }
        f4v c0 = {bb0, bb0, bb0, bb0};
        f4v c1 = {bb1, bb1, bb1, bb1};
        c0 = MFMA16(af, bfr[0], c0);
        c1 = MFMA16(af, bfr[1], c1);
#pragma unroll
        for (int r = 0; r < 4; ++r) {
            int row = n0 + mt * 16 + hi * 4 + r;
            agg[row * 32 + col]      = c0[r];
            agg[row * 32 + 16 + col] = c1[r];
        }
    }
}

// ------------------------------------------------------- fused edge path ----
// block = 256 (4 waves), 48 edges/wave, 192 edges/block, grid 1280.
// c-loop is BARRIER-FREE: w2 fragments are read per-wave straight from
// global (L2-resident, 264 KB shared by all blocks). One barrier total.
__launch_bounds__(256, 3)
__global__ void edge_kernel(const float* __restrict__ x,
                            const float* __restrict__ ea,
                            const int*   __restrict__ eidx,
                            const unsigned short* __restrict__ w1p,
                            const unsigned short* __restrict__ w2p,
                            const float* __restrict__ b1,
                            const float* __restrict__ b2,
                            float* __restrict__ agg)
{
    __shared__ __align__(16) unsigned char smem[37632];
    unsigned short* hscr = (unsigned short*)smem;            // [4][16][200] (25600 B)
    unsigned short* xs   = (unsigned short*)(smem + 25600);  // [192][22] bf16 (8448 B)
    float*          b2l  = (float*)(smem + 34048);           // [704] (2816 B)
    int*            dstl = (int*)(smem + 36864);             // [192] (768 B)

    const int tid  = threadIdx.x;
    const int wave = tid >> 6, lane = tid & 63;
    const int hi = lane >> 4, col = lane & 15;
    const int e0 = blockIdx.x * 192;

    // stage gathered x rows (one thread per edge), dst indices, b2
    if (tid < 192) {
        int s = eidx[e0 + tid];
        dstl[tid] = eidx[E_TOT + e0 + tid];
        const float2* p = (const float2*)&x[s * 22];
#pragma unroll
        for (int c2 = 0; c2 < 11; ++c2) {
            float2 v = p[c2];
            unsigned pk = (unsigned)f2bf(v.x) | ((unsigned)f2bf(v.y) << 16);
            *(unsigned*)&xs[tid * 22 + 2 * c2] = pk;
        }
    }
    for (int idx = tid; idx < 704; idx += 256) b2l[idx] = b2[idx];

    // ---- layer 1: h = relu(ea @ w1 + b1), wave-private, barrier-free ----
    s8v w1f[12];
#pragma unroll
    for (int nt = 0; nt < 12; ++nt) w1f[nt] = *(const s8v*)(w1p + (nt * 64 + lane) * 8);
    float b1v[12];
#pragma unroll
    for (int nt = 0; nt < 12; ++nt) b1v[nt] = b1[nt * 16 + col];

    s8v haf[3][6];
#pragma unroll
    for (int mt = 0; mt < 3; ++mt) {
        int er = e0 + wave * 48 + mt * 16 + col;
        s8v af;
#pragma unroll
        for (int i = 0; i < 8; ++i) {
            int k = hi * 8 + i;
            af[i] = (short)f2bf(k < 30 ? ea[er * 30 + k] : 0.f);
        }
        f4v hc[12];
#pragma unroll
        for (int nt = 0; nt < 12; ++nt) {
            f4v z = {0.f, 0.f, 0.f, 0.f};
            hc[nt] = MFMA16(af, w1f[nt], z);
        }
#pragma unroll
        for (int nt = 0; nt < 12; ++nt)
#pragma unroll
            for (int r = 0; r < 4; ++r) {
                float v = hc[nt][r] + b1v[nt];
                v = v > 0.f ? v : 0.f;
                hscr[(wave * 16 + hi * 4 + r) * 200 + nt * 16 + col] = f2bf(v);
            }
#pragma unroll
        for (int s = 0; s < 6; ++s)
            haf[mt][s] = *(const s8v*)&hscr[(wave * 16 + col) * 200 + s * 32 + hi * 8];
    }

    __syncthreads();   // staging (xs/b2l/dstl) visible; only barrier in kernel

    f4v msg[3][2];
#pragma unroll
    for (int mt = 0; mt < 3; ++mt)
#pragma unroll
        for (int t = 0; t < 2; ++t) msg[mt][t] = (f4v){0.f, 0.f, 0.f, 0.f};

    // ---- layer 2 + einsum: barrier-free, B-frags straight from L2 ----
    // per-c element stride in w2p is 6144 shorts (= 12288 BYTES -- round-4 bug
    // used the byte count as an element index and read garbage past w2p).
    for (int cp = 0; cp < 11; ++cp) {
        unsigned xu[12];
#pragma unroll
        for (int mt = 0; mt < 3; ++mt)
#pragma unroll
            for (int r = 0; r < 4; ++r)
                xu[mt * 4 + r] = *(const unsigned*)&xs[(wave * 48 + mt * 16 + hi * 4 + r) * 22 + 2 * cp];

#pragma unroll
        for (int sub = 0; sub < 2; ++sub) {
            const int c = 2 * cp + sub;
            f4v pacc[3][2];
#pragma unroll
            for (int t = 0; t < 2; ++t) {
                s8v bfr[6];
#pragma unroll
                for (int s = 0; s < 6; ++s)
                    bfr[s] = *(const s8v*)&w2p[c * 6144 + ((t * 6 + s) * 64 + lane) * 8];
                float bv = b2l[c * 32 + t * 16 + col];
#pragma unroll
                for (int mt = 0; mt < 3; ++mt) pacc[mt][t] = (f4v){bv, bv, bv, bv};
#pragma unroll
                for (int s = 0; s < 6; ++s)
#pragma unroll
                    for (int mt = 0; mt < 3; ++mt)
                        pacc[mt][t] = MFMA16(haf[mt][s], bfr[s], pacc[mt][t]);
            }
#pragma unroll
            for (int mt = 0; mt < 3; ++mt)
#pragma unroll
                for (int r = 0; r < 4; ++r) {
                    float xv = sub ? bfhi(xu[mt * 4 + r]) : bflo(xu[mt * 4 + r]);
                    msg[mt][0][r] += xv * pacc[mt][0][r];
                    msg[mt][1][r] += xv * pacc[mt][1][r];
                }
        }
    }

    // ---- scatter-add ----
#pragma unroll
    for (int mt = 0; mt < 3; ++mt)
#pragma unroll
        for (int r = 0; r < 4; ++r) {
            int e = wave * 48 + mt * 16 + hi * 4 + r;
            int d = dstl[e];
            atomicAdd(&agg[d * 32 + col],      msg[mt][0][r]);
            atomicAdd(&agg[d * 32 + 16 + col], msg[mt][1][r]);
        }
}

// ------------------------------------------------------- fused dense head ----
// 1 wave per block, 16 graphs (= 192 nodes) per block, grid 512.
// relu(agg) -> gls (bf16, LDS) -> h1(384->96) -> h2(96->48) -> h3(48->132).
__launch_bounds__(64)
__global__ void head_kernel(const float* __restrict__ agg,
                            const unsigned short* __restrict__ l1p,
                            const unsigned short* __restrict__ l2p,
                            const unsigned short* __restrict__ l3p,
                            const float* __restrict__ l1b,
                            const float* __restrict__ l2b,
                            const float* __restrict__ l3b,
                            float* __restrict__ out)
{
    __shared__ __align__(16) unsigned short gls[16 * 392];   // 12544 B, stride-392 pad
    __shared__ __align__(16) unsigned short a1s[16 * 104];   // 3328 B
    __shared__ __align__(16) unsigned short a2s[16 * 56];    // 1792 B

    const int lane = threadIdx.x & 63;
    const int hi = lane >> 4, col = lane & 15;
    const int r0 = blockIdx.x * 16;           // graph rows

    // ---- relu(agg) -> gls bf16 : contiguous 192*32 f32 = [16][384] ----
    const f4v* a4 = (const f4v*)(agg + (size_t)r0 * 384);
#pragma unroll
    for (int it = 0; it < 24; ++it) {
        int q = it * 64 + lane;
        f4v v = a4[q];
#pragma unroll
        for (int j = 0; j < 4; ++j) v[j] = v[j] > 0.f ? v[j] : 0.f;
        int row = q / 96, coloff = (q - row * 96) * 4;
        unsigned pk0 = (unsigned)f2bf(v[0]) | ((unsigned)f2bf(v[1]) << 16);
        unsigned pk1 = (unsigned)f2bf(v[2]) | ((unsigned)f2bf(v[3]) << 16);
        *(unsigned*)&gls[row * 392 + coloff]     = pk0;
        *(unsigned*)&gls[row * 392 + coloff + 2] = pk1;
    }
    // wave-private LDS: in-wave ordering via lgkmcnt, no barrier needed

    // ---- h1: 384 -> 96 ----
    f4v acc1[6];
#pragma unroll
    for (int nt = 0; nt < 6; ++nt) {
        float bv = l1b[nt * 16 + col];
        acc1[nt] = (f4v){bv, bv, bv, bv};
    }
#pragma unroll
    for (int s = 0; s < 12; ++s) {
        s8v a = *(const s8v*)&gls[col * 392 + s * 32 + hi * 8];
#pragma unroll
        for (int nt = 0; nt < 6; ++nt) {
            s8v b = *(const s8v*)&l1p[((nt * 12 + s) * 64 + lane) * 8];
            acc1[nt] = MFMA16(a, b, acc1[nt]);
        }
    }
#pragma unroll
    for (int nt = 0; nt < 6; ++nt)
#pragma unroll
        for (int r = 0; r < 4; ++r) {
            float v = acc1[nt][r];
            a1s[(hi * 4 + r) * 104 + nt * 16 + col] = f2bf(v > 0.f ? v : 0.f);
        }

    // ---- h2: 96 -> 48 ----
    f4v acc2[3];
#pragma unroll
    for (int nt = 0; nt < 3; ++nt) {
        float bv = l2b[nt * 16 + col];
        acc2[nt] = (f4v){bv, bv, bv, bv};
    }
#pragma unroll
    for (int s = 0; s < 3; ++s) {
        s8v a = *(const s8v*)&a1s[col * 104 + s * 32 + hi * 8];
#pragma unroll
        for (int nt = 0; nt < 3; ++nt) {
            s8v b = *(const s8v*)&l2p[((nt * 3 + s) * 64 + lane) * 8];
            acc2[nt] = MFMA16(a, b, acc2[nt]);
        }
    }
#pragma unroll
    for (int nt = 0; nt < 3; ++nt)
#pragma unroll
        for (int r = 0; r < 4; ++r) {
            float v = acc2[nt][r];
            a2s[(hi * 4 + r) * 56 + nt * 16 + col] = f2bf(v > 0.f ? v : 0.f);
        }

    // ---- h3: 48 -> 132 ----
    f4v acc3[9];
#pragma unroll
    for (int nt = 0; nt < 9; ++nt) {
        int oc = nt * 16 + col;
        float bv = oc < 132 ? l3b[oc] : 0.f;
        acc3[nt] = (f4v){bv, bv, bv, bv};
    }
#pragma unroll
    for (int s = 0; s < 2; ++s) {
        s8v a;
        if (s == 1 && hi >= 2) a = (s8v)0;
        else a = *(const s8v*)&a2s[col * 56 + s * 32 + hi * 8];
#pragma unroll
        for (int nt = 0; nt < 9; ++nt) {
            s8v b = *(const s8v*)&l3p[((nt * 2 + s) * 64 + lane) * 8];
            acc3[nt] = MFMA16(a, b, acc3[nt]);
        }
    }
#pragma unroll
    for (int nt = 0; nt < 9; ++nt) {
        int oc = nt * 16 + col;
        if (oc < 132) {
#pragma unroll
            for (int r = 0; r < 4; ++r) {
                float v = acc3[nt][r];
                out[(r0 + hi * 4 + r) * 132 + oc] = v > 0.f ? v : 0.f;
            }
        }
    }
}

// ---------------------------------------------------------------- launch ----
extern "C" void kernel_launch(void* const* d_in, const int* in_sizes, int n_in,
                              void* d_out, int out_size, void* d_ws, size_t ws_size,
                              hipStream_t stream)
{
    const float* x     = (const float*)d_in[0];
    const float* ea    = (const float*)d_in[1];
    const int*   ei    = (const int*)d_in[2];
    const float* w1    = (const float*)d_in[3];
    const float* b1    = (const float*)d_in[4];
    const float* w2    = (const float*)d_in[5];
    const float* b2    = (const float*)d_in[6];
    const float* root1 = (const float*)d_in[7];
    const float* bias1 = (const float*)d_in[8];
    const float* l1w   = (const float*)d_in[9];
    const float* l1b   = (const float*)d_in[10];
    const float* l2w   = (const float*)d_in[11];
    const float* l2b   = (const float*)d_in[12];
    const float* l3w   = (const float*)d_in[13];
    const float* l3b   = (const float*)d_in[14];
    float* out = (float*)d_out;

    char* ws = (char*)d_ws;
    unsigned short* w1p = (unsigned short*)(ws + 0);
    unsigned short* w2p = (unsigned short*)(ws + 12288);
    unsigned short* l1p = (unsigned short*)(ws + 282624);
    unsigned short* l2p = (unsigned short*)(ws + 356352);
    unsigned short* l3p = (unsigned short*)(ws + 365568);
    float*          agg = (float*)(ws + 384000);

    pack_kernel<<<750, 256, 0, stream>>>(w1, w2, l1w, l2w, l3w, w1p, w2p, l1p, l2p, l3p);
    init_kernel<<<384, 256, 0, stream>>>(x, root1, bias1, agg);
    edge_kernel<<<1280, 256, 0, stream>>>(x, ea, ei, w1p, w2p, b1, b2, agg);
    head_kernel<<<512, 64, 0, stream>>>(agg, l1p, l2p, l3p, l1b, l2b, l3b, out);
}

// Round 6
// 198.211 us; speedup vs baseline: 1.4473x; 1.4473x over previous
//
#include <hip/hip_runtime.h>
#include <hip/hip_bf16.h>

typedef short s8v __attribute__((ext_vector_type(8)));
typedef float f4v __attribute__((ext_vector_type(4)));

#define MFMA16(A,B,C) __builtin_amdgcn_mfma_f32_16x16x32_bf16((A),(B),(C),0,0,0)

#define E_TOT 245760
#define N_TOT 98304

__device__ __forceinline__ unsigned short f2bf(float f) {
    unsigned u = __builtin_bit_cast(unsigned, f);
    u += 0x7fffu + ((u >> 16) & 1u);
    return (unsigned short)(u >> 16);
}
__device__ __forceinline__ float bflo(unsigned u) {
    return __builtin_bit_cast(float, u << 16);
}
__device__ __forceinline__ float bfhi(unsigned u) {
    return __builtin_bit_cast(float, u & 0xffff0000u);
}
__device__ __forceinline__ void gload_lds16(const void* g, void* l) {
    __builtin_amdgcn_global_load_lds(
        (const __attribute__((address_space(1))) void*)g,
        (__attribute__((address_space(3))) void*)l, 16, 0, 0);
}

// ---------------------------------------------------------------- prep ----
// blockIdx < 750  : pack weights into MFMA B-fragment layouts (bf16)
// blockIdx >= 750 : init agg = x @ root1 + bias1 (f32)
// w1p : [12nt][64][8]            6144   bf16   (K 30->32 pad)      pos-space
// w2p : [22c][2t][6s][64][8]     135168 bf16 (per-c stride 6144)   src-space
// l1p : [6nt][12s][64][8]        36864  bf16                       src-space
// l2p : [3nt][3s][64][8]         4608   bf16                       src-space
// l3p : [9nt][2s][64][8]         9216   bf16  (K->64, N->144 pad)  pos-space
__launch_bounds__(256)
__global__ void prep_kernel(const float* __restrict__ w1, const float* __restrict__ w2,
                            const float* __restrict__ l1w, const float* __restrict__ l2w,
                            const float* __restrict__ l3w,
                            unsigned short* __restrict__ w1p, unsigned short* __restrict__ w2p,
                            unsigned short* __restrict__ l1p, unsigned short* __restrict__ l2p,
                            unsigned short* __restrict__ l3p,
                            const float* __restrict__ x, const float* __restrict__ root1,
                            const float* __restrict__ bias1, float* __restrict__ agg)
{
    if (blockIdx.x < 750) {
        int idx = blockIdx.x * 256 + threadIdx.x;
        if (idx >= 192000) return;
        if (idx < 6144) {                       // w1p, position-space (padded)
            int i = idx & 7, l = (idx >> 3) & 63, nt = idx >> 9;
            int k = (l >> 4) * 8 + i, col = nt * 16 + (l & 15);
            w1p[idx] = f2bf(k < 30 ? w1[k * 192 + col] : 0.f);
        } else if (idx < 141312) {              // w2p, source-space (coalesced reads)
            int e = idx - 6144;
            int k = e / 704, j = e - k * 704;
            int c = j >> 5, t = (j >> 4) & 1, colv = j & 15;
            int s = k >> 5, hi = (k >> 3) & 3, i = k & 7;
            w2p[((c * 2 + t) * 6 + s) * 512 + (hi * 16 + colv) * 8 + i] = f2bf(w2[e]);
        } else if (idx < 178176) {              // l1p, source-space
            int e = idx - 141312;
            int k = e / 96, j = e - k * 96;
            int s = k >> 5, hi = (k >> 3) & 3, i = k & 7;
            int nt = j >> 4, colv = j & 15;
            l1p[(nt * 12 + s) * 512 + (hi * 16 + colv) * 8 + i] = f2bf(l1w[e]);
        } else if (idx < 182784) {              // l2p, source-space
            int e = idx - 178176;
            int k = e / 48, j = e - k * 48;
            int s = k >> 5, hi = (k >> 3) & 3, i = k & 7;
            int nt = j >> 4, colv = j & 15;
            l2p[(nt * 3 + s) * 512 + (hi * 16 + colv) * 8 + i] = f2bf(l2w[e]);
        } else {                                // l3p, position-space (padded)
            int e = idx - 182784;
            int i = e & 7, l = (e >> 3) & 63, rest = e >> 9;
            int s = rest & 1, nt = rest >> 1;
            int k = s * 32 + (l >> 4) * 8 + i, j = nt * 16 + (l & 15);
            l3p[e] = f2bf((k < 48 && j < 132) ? l3w[k * 132 + j] : 0.f);
        }
        return;
    }

    // ---- init: agg = x @ root1 + bias1 ----
    const int tid = threadIdx.x, wave = tid >> 6, lane = tid & 63;
    const int hi = lane >> 4, col = lane & 15;
    const int n0 = (blockIdx.x - 750) * 256 + wave * 64;

    s8v bfr[2];
#pragma unroll
    for (int nt = 0; nt < 2; ++nt)
#pragma unroll
        for (int i = 0; i < 8; ++i) {
            int k = hi * 8 + i;
            bfr[nt][i] = (short)f2bf(k < 22 ? root1[k * 32 + nt * 16 + col] : 0.f);
        }
    float bb0 = bias1[col], bb1 = bias1[16 + col];

#pragma unroll
    for (int mt = 0; mt < 4; ++mt) {
        int node = n0 + mt * 16 + col;
        s8v af;
        if (hi < 2) {
            const float2* p = (const float2*)&x[node * 22 + hi * 8];
            float2 t0 = p[0], t1 = p[1], t2 = p[2], t3 = p[3];
            af[0] = (short)f2bf(t0.x); af[1] = (short)f2bf(t0.y);
            af[2] = (short)f2bf(t1.x); af[3] = (short)f2bf(t1.y);
            af[4] = (short)f2bf(t2.x); af[5] = (short)f2bf(t2.y);
            af[6] = (short)f2bf(t3.x); af[7] = (short)f2bf(t3.y);
        } else if (hi == 2) {
            const float2* p = (const float2*)&x[node * 22 + 16];
            float2 t0 = p[0], t1 = p[1], t2 = p[2];
            af[0] = (short)f2bf(t0.x); af[1] = (short)f2bf(t0.y);
            af[2] = (short)f2bf(t1.x); af[3] = (short)f2bf(t1.y);
            af[4] = (short)f2bf(t2.x); af[5] = (short)f2bf(t2.y);
            af[6] = 0; af[7] = 0;
        } else {
            af = (s8v)0;
        }
        f4v c0 = {bb0, bb0, bb0, bb0};
        f4v c1 = {bb1, bb1, bb1, bb1};
        c0 = MFMA16(af, bfr[0], c0);
        c1 = MFMA16(af, bfr[1], c1);
#pragma unroll
        for (int r = 0; r < 4; ++r) {
            int row = n0 + mt * 16 + hi * 4 + r;
            agg[row * 32 + col]      = c0[r];
            agg[row * 32 + 16 + col] = c1[r];
        }
    }
}

// ------------------------------------------------------- fused edge path ----
// block = 256 (4 waves), 48 edges/wave, 192 edges/block, grid 1280.
// LDS-staged w2, double-buffered at 2-c granularity: 13 barriers total,
// 72-MFMA stretch per barrier. LDS 61184 B -> 2 blocks/CU.
__launch_bounds__(256, 2)
__global__ void edge_kernel(const float* __restrict__ x,
                            const float* __restrict__ ea,
                            const int*   __restrict__ eidx,
                            const unsigned short* __restrict__ w1p,
                            const unsigned short* __restrict__ w2p,
                            const float* __restrict__ b1,
                            const float* __restrict__ b2,
                            float* __restrict__ agg)
{
    __shared__ __align__(16) unsigned char smem[61184];
    unsigned short* w2c  = (unsigned short*)smem;            // 2 bufs x (2c x 6144) shorts = 49152 B
    unsigned short* hscr = (unsigned short*)smem;            // [4][16][200] (25600 B) - union, layer1 only
    unsigned short* xs   = (unsigned short*)(smem + 49152);  // [192][22] bf16 (8448 B)
    float*          b2l  = (float*)(smem + 57600);           // [704] (2816 B)
    int*            dstl = (int*)(smem + 60416);             // [192] (768 B)

    const int tid  = threadIdx.x;
    const int wave = tid >> 6, lane = tid & 63;
    const int hi = lane >> 4, col = lane & 15;
    const int e0 = blockIdx.x * 192;

    // stage gathered x rows (one thread per edge), dst indices, b2
    if (tid < 192) {
        int s = eidx[e0 + tid];
        dstl[tid] = eidx[E_TOT + e0 + tid];
        const float2* p = (const float2*)&x[s * 22];
#pragma unroll
        for (int c2 = 0; c2 < 11; ++c2) {
            float2 v = p[c2];
            unsigned pk = (unsigned)f2bf(v.x) | ((unsigned)f2bf(v.y) << 16);
            *(unsigned*)&xs[tid * 22 + 2 * c2] = pk;
        }
    }
    for (int idx = tid; idx < 704; idx += 256) b2l[idx] = b2[idx];

    // ---- layer 1: h = relu(ea @ w1 + b1), wave-private, barrier-free ----
    s8v w1f[12];
#pragma unroll
    for (int nt = 0; nt < 12; ++nt) w1f[nt] = *(const s8v*)(w1p + (nt * 64 + lane) * 8);
    float b1v[12];
#pragma unroll
    for (int nt = 0; nt < 12; ++nt) b1v[nt] = b1[nt * 16 + col];

    s8v haf[3][6];
#pragma unroll
    for (int mt = 0; mt < 3; ++mt) {
        int er = e0 + wave * 48 + mt * 16 + col;
        s8v af;
#pragma unroll
        for (int i = 0; i < 8; ++i) {
            int k = hi * 8 + i;
            af[i] = (short)f2bf(k < 30 ? ea[er * 30 + k] : 0.f);
        }
        f4v hc[12];
#pragma unroll
        for (int nt = 0; nt < 12; ++nt) {
            f4v z = {0.f, 0.f, 0.f, 0.f};
            hc[nt] = MFMA16(af, w1f[nt], z);
        }
#pragma unroll
        for (int nt = 0; nt < 12; ++nt)
#pragma unroll
            for (int r = 0; r < 4; ++r) {
                float v = hc[nt][r] + b1v[nt];
                v = v > 0.f ? v : 0.f;
                hscr[(wave * 16 + hi * 4 + r) * 200 + nt * 16 + col] = f2bf(v);
            }
#pragma unroll
        for (int s = 0; s < 6; ++s)
            haf[mt][s] = *(const s8v*)&hscr[(wave * 16 + col) * 200 + s * 32 + hi * 8];
    }

    __syncthreads();   // hscr (union w2c) free; staging (xs/b2l/dstl) visible

    // prestage c-pair 0 into buf0 (12288 shorts = 24576 B = 6 chunks/thread)
#pragma unroll
    for (int q = 0; q < 6; ++q)
        gload_lds16(w2p + (q * 256 + tid) * 8, w2c + (q * 256 + wave * 64) * 8);
    __syncthreads();   // drains vmcnt -> buf0 ready

    f4v msg[3][2];
#pragma unroll
    for (int mt = 0; mt < 3; ++mt)
#pragma unroll
        for (int t = 0; t < 2; ++t) msg[mt][t] = (f4v){0.f, 0.f, 0.f, 0.f};

    // c-loop over 11 pairs, double-buffered, 1 barrier per pair
    for (int cp = 0; cp < 11; ++cp) {
        const int cur = (cp & 1) * 12288;
        // stage next pair into the other buffer (lands under this pair's MFMAs)
        if (cp < 10) {
            const int nxt = 12288 - cur;
#pragma unroll
            for (int q = 0; q < 6; ++q)
                gload_lds16(w2p + (cp + 1) * 12288 + (q * 256 + tid) * 8,
                            w2c + nxt + (q * 256 + wave * 64) * 8);
        }

        unsigned xu[12];
#pragma unroll
        for (int mt = 0; mt < 3; ++mt)
#pragma unroll
            for (int r = 0; r < 4; ++r)
                xu[mt * 4 + r] = *(const unsigned*)&xs[(wave * 48 + mt * 16 + hi * 4 + r) * 22 + 2 * cp];

#pragma unroll
        for (int sub = 0; sub < 2; ++sub) {
            f4v pacc[3][2];
#pragma unroll
            for (int t = 0; t < 2; ++t) {
                float bv = b2l[(2 * cp + sub) * 32 + t * 16 + col];
#pragma unroll
                for (int mt = 0; mt < 3; ++mt) pacc[mt][t] = (f4v){bv, bv, bv, bv};
#pragma unroll
                for (int s = 0; s < 6; ++s) {
                    s8v bfr = *(const s8v*)&w2c[cur + sub * 6144 + ((t * 6 + s) * 64 + lane) * 8];
#pragma unroll
                    for (int mt = 0; mt < 3; ++mt)
                        pacc[mt][t] = MFMA16(haf[mt][s], bfr, pacc[mt][t]);
                }
            }
#pragma unroll
            for (int mt = 0; mt < 3; ++mt)
#pragma unroll
                for (int r = 0; r < 4; ++r) {
                    float xv = sub ? bfhi(xu[mt * 4 + r]) : bflo(xu[mt * 4 + r]);
                    msg[mt][0][r] += xv * pacc[mt][0][r];
                    msg[mt][1][r] += xv * pacc[mt][1][r];
                }
        }
        __syncthreads();   // next buf staged (vm drained), cur-buf reads done
    }

    // ---- scatter-add ----
#pragma unroll
    for (int mt = 0; mt < 3; ++mt)
#pragma unroll
        for (int r = 0; r < 4; ++r) {
            int e = wave * 48 + mt * 16 + hi * 4 + r;
            int d = dstl[e];
            atomicAdd(&agg[d * 32 + col],      msg[mt][0][r]);
            atomicAdd(&agg[d * 32 + 16 + col], msg[mt][1][r]);
        }
}

// ------------------------------------------------------- fused dense head ----
// 1 wave per block, 16 graphs (= 192 nodes) per block, grid 512.
// relu(agg) -> gls (bf16, LDS) -> h1(384->96) -> h2(96->48) -> h3(48->132).
__launch_bounds__(64)
__global__ void head_kernel(const float* __restrict__ agg,
                            const unsigned short* __restrict__ l1p,
                            const unsigned short* __restrict__ l2p,
                            const unsigned short* __restrict__ l3p,
                            const float* __restrict__ l1b,
                            const float* __restrict__ l2b,
                            const float* __restrict__ l3b,
                            float* __restrict__ out)
{
    __shared__ __align__(16) unsigned short gls[16 * 392];   // 12544 B, stride-392 pad
    __shared__ __align__(16) unsigned short a1s[16 * 104];   // 3328 B
    __shared__ __align__(16) unsigned short a2s[16 * 56];    // 1792 B

    const int lane = threadIdx.x & 63;
    const int hi = lane >> 4, col = lane & 15;
    const int r0 = blockIdx.x * 16;           // graph rows

    // ---- relu(agg) -> gls bf16 : contiguous 192*32 f32 = [16][384] ----
    const f4v* a4 = (const f4v*)(agg + (size_t)r0 * 384);
#pragma unroll
    for (int it = 0; it < 24; ++it) {
        int q = it * 64 + lane;
        f4v v = a4[q];
#pragma unroll
        for (int j = 0; j < 4; ++j) v[j] = v[j] > 0.f ? v[j] : 0.f;
        int row = q / 96, coloff = (q - row * 96) * 4;
        unsigned pk0 = (unsigned)f2bf(v[0]) | ((unsigned)f2bf(v[1]) << 16);
        unsigned pk1 = (unsigned)f2bf(v[2]) | ((unsigned)f2bf(v[3]) << 16);
        *(unsigned*)&gls[row * 392 + coloff]     = pk0;
        *(unsigned*)&gls[row * 392 + coloff + 2] = pk1;
    }
    // wave-private LDS: in-wave ordering via lgkmcnt, no barrier needed

    // ---- h1: 384 -> 96 ----
    f4v acc1[6];
#pragma unroll
    for (int nt = 0; nt < 6; ++nt) {
        float bv = l1b[nt * 16 + col];
        acc1[nt] = (f4v){bv, bv, bv, bv};
    }
#pragma unroll
    for (int s = 0; s < 12; ++s) {
        s8v a = *(const s8v*)&gls[col * 392 + s * 32 + hi * 8];
#pragma unroll
        for (int nt = 0; nt < 6; ++nt) {
            s8v b = *(const s8v*)&l1p[((nt * 12 + s) * 64 + lane) * 8];
            acc1[nt] = MFMA16(a, b, acc1[nt]);
        }
    }
#pragma unroll
    for (int nt = 0; nt < 6; ++nt)
#pragma unroll
        for (int r = 0; r < 4; ++r) {
            float v = acc1[nt][r];
            a1s[(hi * 4 + r) * 104 + nt * 16 + col] = f2bf(v > 0.f ? v : 0.f);
        }

    // ---- h2: 96 -> 48 ----
    f4v acc2[3];
#pragma unroll
    for (int nt = 0; nt < 3; ++nt) {
        float bv = l2b[nt * 16 + col];
        acc2[nt] = (f4v){bv, bv, bv, bv};
    }
#pragma unroll
    for (int s = 0; s < 3; ++s) {
        s8v a = *(const s8v*)&a1s[col * 104 + s * 32 + hi * 8];
#pragma unroll
        for (int nt = 0; nt < 3; ++nt) {
            s8v b = *(const s8v*)&l2p[((nt * 3 + s) * 64 + lane) * 8];
            acc2[nt] = MFMA16(a, b, acc2[nt]);
        }
    }
#pragma unroll
    for (int nt = 0; nt < 3; ++nt)
#pragma unroll
        for (int r = 0; r < 4; ++r) {
            float v = acc2[nt][r];
            a2s[(hi * 4 + r) * 56 + nt * 16 + col] = f2bf(v > 0.f ? v : 0.f);
        }

    // ---- h3: 48 -> 132 ----
    f4v acc3[9];
#pragma unroll
    for (int nt = 0; nt < 9; ++nt) {
        int oc = nt * 16 + col;
        float bv = oc < 132 ? l3b[oc] : 0.f;
        acc3[nt] = (f4v){bv, bv, bv, bv};
    }
#pragma unroll
    for (int s = 0; s < 2; ++s) {
        s8v a;
        if (s == 1 && hi >= 2) a = (s8v)0;
        else a = *(const s8v*)&a2s[col * 56 + s * 32 + hi * 8];
#pragma unroll
        for (int nt = 0; nt < 9; ++nt) {
            s8v b = *(const s8v*)&l3p[((nt * 2 + s) * 64 + lane) * 8];
            acc3[nt] = MFMA16(a, b, acc3[nt]);
        }
    }
#pragma unroll
    for (int nt = 0; nt < 9; ++nt) {
        int oc = nt * 16 + col;
        if (oc < 132) {
#pragma unroll
            for (int r = 0; r < 4; ++r) {
                float v = acc3[nt][r];
                out[(r0 + hi * 4 + r) * 132 + oc] = v > 0.f ? v : 0.f;
            }
        }
    }
}

// ---------------------------------------------------------------- launch ----
extern "C" void kernel_launch(void* const* d_in, const int* in_sizes, int n_in,
                              void* d_out, int out_size, void* d_ws, size_t ws_size,
                              hipStream_t stream)
{
    const float* x     = (const float*)d_in[0];
    const float* ea    = (const float*)d_in[1];
    const int*   ei    = (const int*)d_in[2];
    const float* w1    = (const float*)d_in[3];
    const float* b1    = (const float*)d_in[4];
    const float* w2    = (const float*)d_in[5];
    const float* b2    = (const float*)d_in[6];
    const float* root1 = (const float*)d_in[7];
    const float* bias1 = (const float*)d_in[8];
    const float* l1w   = (const float*)d_in[9];
    const float* l1b   = (const float*)d_in[10];
    const float* l2w   = (const float*)d_in[11];
    const float* l2b   = (const float*)d_in[12];
    const float* l3w   = (const float*)d_in[13];
    const float* l3b   = (const float*)d_in[14];
    float* out = (float*)d_out;

    char* ws = (char*)d_ws;
    unsigned short* w1p = (unsigned short*)(ws + 0);
    unsigned short* w2p = (unsigned short*)(ws + 12288);
    unsigned short* l1p = (unsigned short*)(ws + 282624);
    unsigned short* l2p = (unsigned short*)(ws + 356352);
    unsigned short* l3p = (unsigned short*)(ws + 365568);
    float*          agg = (float*)(ws + 384000);

    prep_kernel<<<1134, 256, 0, stream>>>(w1, w2, l1w, l2w, l3w, w1p, w2p, l1p, l2p, l3p,
                                          x, root1, bias1, agg);
    edge_kernel<<<1280, 256, 0, stream>>>(x, ea, ei, w1p, w2p, b1, b2, agg);
    head_kernel<<<512, 64, 0, stream>>>(agg, l1p, l2p, l3p, l1b, l2b, l3b, out);
}